// Round 9
// baseline (668.986 us; speedup 1.0000x reference)
//
#include <hip/hip_runtime.h>
#include <hip/hip_bf16.h>

#define BATCH 32
#define SEQ   2048
#define DIM   1024
// GEMM: M = 65536, N = 1024, K = 1024

typedef __attribute__((ext_vector_type(4))) float f32x4;
typedef __attribute__((ext_vector_type(8))) short short8;

static __device__ __forceinline__ ushort f2bf(float x) {
    __hip_bfloat16 h = __float2bfloat16(x);
    union { __hip_bfloat16 h; ushort u; } cv; cv.h = h;
    return cv.u;
}

// async global -> LDS, 16B per lane. LDS dest = wave-uniform base (HW adds lane*16B).
static __device__ __forceinline__ void gll16(const void* g, void* l) {
    __builtin_amdgcn_global_load_lds(
        (const __attribute__((address_space(1))) void*)g,
        (__attribute__((address_space(3))) void*)l, 16, 0, 0);
}

// ---------------- k0a: enc f32 -> bf16, packed in MFMA A-fragment order ----------------
__global__ __launch_bounds__(256) void kAPack(const float* __restrict__ enc,
                                              ushort* __restrict__ apk) {
    int g = blockIdx.x * 256 + threadIdx.x;     // 8,388,608 total
    int lane = g & 63;
    int frag = (g >> 6) & 31;
    int kt   = (g >> 11) & 15;
    int strip = g >> 15;                        // [0,256)
    int mt = frag >> 1, kb = frag & 1;
    int row = (strip << 8) + (mt << 4) + (lane & 15);
    int k0  = (kt << 6) + (kb << 5) + ((lane >> 4) << 3);
    const float* src = enc + (size_t)row * DIM + k0;
    float4 a = *(const float4*)src;
    float4 b = *(const float4*)(src + 4);
    union { ushort us[8]; uint4 u4; } pk;
    pk.us[0] = f2bf(a.x); pk.us[1] = f2bf(a.y); pk.us[2] = f2bf(a.z); pk.us[3] = f2bf(a.w);
    pk.us[4] = f2bf(b.x); pk.us[5] = f2bf(b.y); pk.us[6] = f2bf(b.z); pk.us[7] = f2bf(b.w);
    *(uint4*)(apk + (size_t)g * 8) = pk.u4;
}

// ---------------- k0b: Wh f32 -> bf16, fragment order (4 panels of 256 e) ----------------
__global__ __launch_bounds__(256) void kWhPack(const float* __restrict__ Wh,
                                               ushort* __restrict__ bpk) {
    int g = blockIdx.x * 256 + threadIdx.x;     // 131072 total
    int lane = g & 63;
    int frag = (g >> 6) & 31;
    int kt   = (g >> 11) & 15;
    int nb   = g >> 15;                         // [0,4)
    int ebl = frag >> 1, kbit = frag & 1;
    int e  = (nb << 8) + (ebl << 4) + (lane & 15);
    int k0 = (kt << 6) + (kbit << 5) + ((lane >> 4) << 3);
    const float* src = Wh + (size_t)e * DIM + k0;
    float4 a = *(const float4*)src;
    float4 b = *(const float4*)(src + 4);
    union { ushort us[8]; uint4 u4; } pk;
    pk.us[0] = f2bf(a.x); pk.us[1] = f2bf(a.y); pk.us[2] = f2bf(a.z); pk.us[3] = f2bf(a.w);
    pk.us[4] = f2bf(b.x); pk.us[5] = f2bf(b.y); pk.us[6] = f2bf(b.z); pk.us[7] = f2bf(b.w);
    *(uint4*)(bpk + (size_t)g * 8) = pk.u4;
}

// ---------------- k0c: base[b,e] = dec[b,:]·Ws[e,:] + bs + bh (+bc) ----------------
__global__ __launch_bounds__(256) void kBase(const float* __restrict__ dh,
                                             const float* __restrict__ Ws,
                                             const float* __restrict__ bs,
                                             const float* __restrict__ bh,
                                             const float* __restrict__ bc,
                                             const int* __restrict__ uc,
                                             float* __restrict__ base) {
    __shared__ float dec[8][DIM];
    int ec = blockIdx.x >> 2;
    int bg = blockIdx.x & 3;
    int b0 = bg * 8, e0 = ec * 32;
    int tid = threadIdx.x;
    for (int i = tid; i < 8 * DIM; i += 256) {
        int bb = i >> 10, d = i & 1023;
        float vdec = (d < 512) ? dh[(b0 + bb) * 512 + d]
                               : dh[BATCH * 512 + (b0 + bb) * 512 + d - 512];
        dec[bb][d] = vdec;
    }
    __syncthreads();
    int el = tid >> 3, ds = tid & 7;
    int e = e0 + el;
    float acc[8] = {0.f, 0.f, 0.f, 0.f, 0.f, 0.f, 0.f, 0.f};
    const float* wrow = Ws + (size_t)e * DIM;
    for (int i = 0; i < 128; ++i) {
        int d = i * 8 + ds;
        float wv = wrow[d];
#pragma unroll
        for (int bb = 0; bb < 8; ++bb) acc[bb] += wv * dec[bb][d];
    }
#pragma unroll
    for (int bb = 0; bb < 8; ++bb) {
        float s = acc[bb];
        s += __shfl_xor(s, 1); s += __shfl_xor(s, 2); s += __shfl_xor(s, 4);
        acc[bb] = s;
    }
    if (ds == 0) {
        float bias = bs[e] + bh[e] + ((*uc) ? bc[e] : 0.0f);
#pragma unroll
        for (int bb = 0; bb < 8; ++bb) base[(b0 + bb) * DIM + e] = acc[bb] + bias;
    }
}

// ---------------- k2: 8-phase fine-interleaved 256x256 GEMM + tanh + v-dot ----------------
// BM=BN=256, BK=64, 512 thr = 8 waves (2 wm x 4 wn), wave tile 128x64, acc[8][4].
// Iteration = 2 K-tiles (even->buf0, odd->buf1), 8 phases; per phase:
//   {stage 1 half-tile (2 gll16/wave) ; quadrant ds_read (4-12 b128) ; bar ;
//    setprio(1) 16 MFMA setprio(0) ; [seam vmcnt(0)] ; bar}
// Odd tile staged ph1-4 (consumed ph5-8 same iter); even tile t+2 staged ph5-8
// (consumed next iter ph1-4). Seams at ph4/ph8 are minimal waits (nothing else in flight).
__global__ __launch_bounds__(512, 2) void kScore(const ushort* __restrict__ apk,
                                                 const ushort* __restrict__ bpk,
                                                 const float* __restrict__ base,
                                                 const float* __restrict__ pc,
                                                 const float* __restrict__ Wc,
                                                 const float* __restrict__ vv,
                                                 const int* __restrict__ uc,
                                                 float* __restrict__ scorep) {
    __shared__ ushort Al[2][16384];   // 32 frags x 1KB per buf
    __shared__ ushort Bl[2][16384];
    __shared__ float red[4][256];

    const int tid = threadIdx.x;
    const int w = tid >> 6, lane = tid & 63;
    const int q = lane >> 4, l15 = lane & 15;
    const int wm = w >> 2, wn = w & 3;

    // XCD swizzle: xcd x owns m-tiles [x*32,(x+1)*32); 4 nbk of one m-tile adjacent.
    const int x = blockIdx.x & 7;
    const int j = blockIdx.x >> 3;          // [0,128)
    const int ms = (x << 5) + (j >> 2);     // m-tile [0,256)
    const int nbk = j & 3;                  // n-panel [0,4)
    const int b = ms >> 3;
    const int s0 = (ms & 7) << 8;

    const ushort* abase = apk + ((size_t)ms << 18);
    const ushort* bbase = bpk + ((size_t)nbk << 18);

    short8 a_[4][2];   // current quadrant A frags (4 mf x 2 kb)
    short8 b_[2][2];   // current quadrant B frags (2 nb x 2 kb)
    f32x4 acc[8][4] = {};

#define STG_A(KT, BUF, H) do { \
    const ushort* s_ = abase + ((size_t)(KT) << 14); \
    int f_ = ((H) << 4) + (w << 1); \
    gll16(s_ + ((size_t)f_ << 9) + (lane << 3), &Al[BUF][f_ << 9]); \
    gll16(s_ + ((size_t)(f_ + 1) << 9) + (lane << 3), &Al[BUF][(f_ + 1) << 9]); \
} while (0)

#define STG_B(KT, BUF, H) do { \
    const ushort* s_ = bbase + ((size_t)(KT) << 14); \
    int f_ = ((H) << 4) + (w << 1); \
    gll16(s_ + ((size_t)f_ << 9) + (lane << 3), &Bl[BUF][f_ << 9]); \
    gll16(s_ + ((size_t)(f_ + 1) << 9) + (lane << 3), &Bl[BUF][(f_ + 1) << 9]); \
} while (0)

#define STG_NONE ((void)0)

#define DSA(BUFC, MH, MF, KB) \
    a_[MF][KB] = *(const short8*)&Al[BUFC][(((((wm << 3) + ((MH) << 2) + (MF)) << 1) + (KB)) << 9) + (lane << 3)]
#define DSB(BUFC, NH, NB, KB) \
    b_[NB][KB] = *(const short8*)&Bl[BUFC][(((((wn << 2) + ((NH) << 1) + (NB)) << 1) + (KB)) << 9) + (lane << 3)]
#define MM(MH, NH, MF, NB, KB) \
    acc[((MH) << 2) + (MF)][((NH) << 1) + (NB)] = __builtin_amdgcn_mfma_f32_16x16x32_bf16( \
        a_[MF][KB], b_[NB][KB], acc[((MH) << 2) + (MF)][((NH) << 1) + (NB)], 0, 0, 0)

#define PHASE(BUFC, MH, NH, LA, LB, STG, SEAM) do { \
    STG; \
    if (LA) { DSA(BUFC, MH, 0, 0); DSA(BUFC, MH, 0, 1); DSA(BUFC, MH, 1, 0); DSA(BUFC, MH, 1, 1); \
              DSA(BUFC, MH, 2, 0); DSA(BUFC, MH, 2, 1); DSA(BUFC, MH, 3, 0); DSA(BUFC, MH, 3, 1); } \
    if (LB) { DSB(BUFC, NH, 0, 0); DSB(BUFC, NH, 0, 1); DSB(BUFC, NH, 1, 0); DSB(BUFC, NH, 1, 1); } \
    __builtin_amdgcn_sched_barrier(0); \
    __builtin_amdgcn_s_barrier(); \
    __builtin_amdgcn_sched_barrier(0); \
    __builtin_amdgcn_s_setprio(1); \
    MM(MH, NH, 0, 0, 0); MM(MH, NH, 1, 0, 0); MM(MH, NH, 2, 0, 0); MM(MH, NH, 3, 0, 0); \
    MM(MH, NH, 0, 1, 0); MM(MH, NH, 1, 1, 0); MM(MH, NH, 2, 1, 0); MM(MH, NH, 3, 1, 0); \
    MM(MH, NH, 0, 0, 1); MM(MH, NH, 1, 0, 1); MM(MH, NH, 2, 0, 1); MM(MH, NH, 3, 0, 1); \
    MM(MH, NH, 0, 1, 1); MM(MH, NH, 1, 1, 1); MM(MH, NH, 2, 1, 1); MM(MH, NH, 3, 1, 1); \
    __builtin_amdgcn_s_setprio(0); \
    if (SEAM) { asm volatile("s_waitcnt vmcnt(0)" ::: "memory"); } \
    __builtin_amdgcn_sched_barrier(0); \
    __builtin_amdgcn_s_barrier(); \
    __builtin_amdgcn_sched_barrier(0); \
} while (0)

    // ---- prologue: stage tile 0 -> buf0, drain, sync ----
    STG_A(0, 0, 0); STG_A(0, 0, 1); STG_B(0, 0, 0); STG_B(0, 0, 1);
    asm volatile("s_waitcnt vmcnt(0)" ::: "memory");
    __builtin_amdgcn_sched_barrier(0);
    __builtin_amdgcn_s_barrier();
    __builtin_amdgcn_sched_barrier(0);

    for (int t = 0; t < 8; ++t) {
        const int to = 2 * t + 1;               // odd tile -> buf1 (used ph5-8 this iter)
        const int tn = 2 * t + 2;               // next even tile -> buf0 (used next iter)
        // phases 1-4: compute tile 2t (buf0), stage odd tile -> buf1
        PHASE(0, 0, 0, 1, 1, STG_A(to, 1, 0), 0);
        PHASE(0, 0, 1, 0, 1, STG_A(to, 1, 1), 0);
        PHASE(0, 1, 1, 1, 0, STG_B(to, 1, 0), 0);
        PHASE(0, 1, 0, 0, 1, STG_B(to, 1, 1), 1);   // seam: buf1 ready
        // phases 5-8: compute tile 2t+1 (buf1), stage tile 2t+2 -> buf0
        if (t < 7) {
            PHASE(1, 0, 0, 1, 1, STG_A(tn, 0, 0), 0);
            PHASE(1, 0, 1, 0, 1, STG_A(tn, 0, 1), 0);
            PHASE(1, 1, 1, 1, 0, STG_B(tn, 0, 0), 0);
            PHASE(1, 1, 0, 0, 1, STG_B(tn, 0, 1), 1);  // seam: buf0 ready
        } else {
            PHASE(1, 0, 0, 1, 1, STG_NONE, 0);
            PHASE(1, 0, 1, 0, 1, STG_NONE, 0);
            PHASE(1, 1, 1, 1, 0, STG_NONE, 0);
            PHASE(1, 1, 0, 0, 1, STG_NONE, 0);
        }
    }

    // ---- epilogue: partial score over this block's 256 e ----
    const float ucf = (float)(*uc);
    float basee[4], ve[4], wce[4];
#pragma unroll
    for (int ef = 0; ef < 4; ++ef) {
        int e = (nbk << 8) + ((wn << 2) + ef) * 16 + l15;
        basee[ef] = base[b * DIM + e];
        ve[ef] = vv[e];
        wce[ef] = Wc[e] * ucf;
    }
#pragma unroll
    for (int mf = 0; mf < 8; ++mf) {
#pragma unroll
        for (int r = 0; r < 4; ++r) {
            int rl = (wm << 7) + (mf << 4) + (q << 2) + r;   // row in [0,256)
            float p = pc[b * SEQ + s0 + rl];
            float sp = 0.f;
#pragma unroll
            for (int ef = 0; ef < 4; ++ef) {
                float xv = acc[mf][ef][r] + basee[ef] + p * wce[ef];
                float tt = 1.0f - 2.0f / (1.0f + __expf(2.0f * xv));  // tanh
                sp += tt * ve[ef];
            }
            sp += __shfl_xor(sp, 1);
            sp += __shfl_xor(sp, 2);
            sp += __shfl_xor(sp, 4);
            sp += __shfl_xor(sp, 8);
            if (l15 == 0) red[wn][rl] = sp;
        }
    }
    __syncthreads();
    if (tid < 256) {
        float s = (red[0][tid] + red[1][tid]) + (red[2][tid] + red[3][tid]);
        scorep[nbk * (BATCH * SEQ) + b * SEQ + s0 + tid] = s;  // bv dropped (softmax-invariant)
    }
}

// ---------------- k3: softmax (sum of 4 partials) + mask + renorm + coverage ----------------
__global__ __launch_bounds__(512) void kSoftmax(const float* __restrict__ scorep,
                                                const float* __restrict__ mask,
                                                const float* __restrict__ pc,
                                                float* __restrict__ att,
                                                float* __restrict__ cov,
                                                int write_cov) {
    __shared__ float rmax[8], rsum[8];
    const int BS = BATCH * SEQ;
    int b = blockIdx.x, tid = threadIdx.x;
    int wv = tid >> 6, ln = tid & 63;
    float x[4];
#pragma unroll
    for (int i = 0; i < 4; ++i) {
        int idx = b * SEQ + tid + i * 512;
        x[i] = (scorep[idx] + scorep[BS + idx]) + (scorep[2 * BS + idx] + scorep[3 * BS + idx]);
    }
    float m = fmaxf(fmaxf(x[0], x[1]), fmaxf(x[2], x[3]));
#pragma unroll
    for (int o = 1; o < 64; o <<= 1) m = fmaxf(m, __shfl_xor(m, o));
    if (ln == 0) rmax[wv] = m;
    __syncthreads();
    m = rmax[0];
#pragma unroll
    for (int i = 1; i < 8; ++i) m = fmaxf(m, rmax[i]);

    float ms[4], wm[4];
#pragma unroll
    for (int i = 0; i < 4; ++i) ms[i] = mask[b * SEQ + tid + i * 512];
    float s = 0.f;
#pragma unroll
    for (int i = 0; i < 4; ++i) { wm[i] = __expf(x[i] - m) * ms[i]; s += wm[i]; }
#pragma unroll
    for (int o = 1; o < 64; o <<= 1) s += __shfl_xor(s, o);
    if (ln == 0) rsum[wv] = s;
    __syncthreads();
    s = 0.f;
#pragma unroll
    for (int i = 0; i < 8; ++i) s += rsum[i];
    float inv = 1.0f / s;
#pragma unroll
    for (int i = 0; i < 4; ++i) {
        float wf = wm[i] * inv;
        att[b * SEQ + tid + i * 512] = wf;
        if (write_cov) cov[b * SEQ + tid + i * 512] = pc[b * SEQ + tid + i * 512] + wf;
    }
}

// ---------------- k4: context partials over s-chunks ----------------
__global__ __launch_bounds__(256) void kCtxPart(const float* __restrict__ enc,
                                                const float* __restrict__ att,
                                                float* __restrict__ part) {
    __shared__ float wl[64];
    int bx = blockIdx.x;           // 32 b x 32 s-chunks
    int b = bx >> 5, sc = bx & 31;
    int tid = threadIdx.x;
    if (tid < 64) wl[tid] = att[b * SEQ + sc * 64 + tid];
    __syncthreads();
    const float* basep = enc + ((size_t)(b * SEQ + sc * 64)) * DIM + tid * 4;
    float4 acc = {0.f, 0.f, 0.f, 0.f};
#pragma unroll 4
    for (int i = 0; i < 64; ++i) {
        float w = wl[i];
        float4 xv = *(const float4*)(basep + (size_t)i * DIM);
        acc.x += w * xv.x; acc.y += w * xv.y; acc.z += w * xv.z; acc.w += w * xv.w;
    }
    *(float4*)(part + (size_t)bx * DIM + tid * 4) = acc;
}

// ---------------- k5: deterministic reduce of partials ----------------
__global__ __launch_bounds__(256) void kCtxReduce(const float* __restrict__ part,
                                                  float* __restrict__ ctx) {
    int g = blockIdx.x * 256 + threadIdx.x;  // 32768
    int b = g >> 10, d = g & 1023;
    float s = 0.f;
#pragma unroll
    for (int i = 0; i < 32; ++i) s += part[((size_t)(b * 32 + i) << 10) + d];
    ctx[g] = s;
}

extern "C" void kernel_launch(void* const* d_in, const int* in_sizes, int n_in,
                              void* d_out, int out_size, void* d_ws, size_t ws_size,
                              hipStream_t stream) {
    const float* dh   = (const float*)d_in[0];
    const float* enc  = (const float*)d_in[1];
    const float* mask = (const float*)d_in[2];
    const float* pc   = (const float*)d_in[3];
    const float* Wh   = (const float*)d_in[4];
    const float* bh   = (const float*)d_in[5];
    const float* Ws   = (const float*)d_in[6];
    const float* bs   = (const float*)d_in[7];
    const float* Wc   = (const float*)d_in[8];
    const float* bc   = (const float*)d_in[9];
    const float* vv   = (const float*)d_in[10];
    // d_in[11] = bv: uniform shift of scores -> softmax-invariant -> unused
    const int* uc     = (const int*)d_in[12];

    float* ctx = (float*)d_out;
    float* att = ctx + BATCH * DIM;
    float* cov = att + BATCH * SEQ;
    int write_cov = (out_size >= BATCH * (DIM + 2 * SEQ)) ? 1 : 0;

    // ws layout: apk 128MB | bpk 2MB | base 128KB | scorep 1MB | part 4MB
    ushort* apk  = (ushort*)d_ws;
    ushort* bpk  = apk + (size_t)BATCH * SEQ * DIM;            // +128MB
    float* base   = (float*)(bpk + (size_t)DIM * DIM);         // +2MB
    float* scorep = base + BATCH * DIM;
    float* part   = scorep + 4 * BATCH * SEQ;

    kAPack<<<32768, 256, 0, stream>>>(enc, apk);
    kWhPack<<<512, 256, 0, stream>>>(Wh, bpk);
    kBase<<<128, 256, 0, stream>>>(dh, Ws, bs, bh, bc, uc, base);
    kScore<<<1024, 512, 0, stream>>>(apk, bpk, base, pc, Wc, vv, uc, scorep);
    kSoftmax<<<BATCH, 512, 0, stream>>>(scorep, mask, pc, att, cov, write_cov);
    kCtxPart<<<1024, 256, 0, stream>>>(enc, att, part);
    kCtxReduce<<<128, 256, 0, stream>>>(part, ctx);
}

// Round 10
// 301.521 us; speedup vs baseline: 2.2187x; 2.2187x over previous
//
#include <hip/hip_runtime.h>
#include <hip/hip_bf16.h>

#define BATCH 32
#define SEQ   2048
#define DIM   1024
// GEMM: M = 65536, N = 1024, K = 1024

typedef __attribute__((ext_vector_type(4))) float f32x4;
typedef __attribute__((ext_vector_type(8))) short short8;

static __device__ __forceinline__ ushort f2bf(float x) {
    __hip_bfloat16 h = __float2bfloat16(x);
    union { __hip_bfloat16 h; ushort u; } cv; cv.h = h;
    return cv.u;
}
static __device__ __forceinline__ float bf2f(ushort u) {
    union { unsigned int i; float f; } cv; cv.i = ((unsigned int)u) << 16;
    return cv.f;
}

// async global -> LDS, 16B per lane. LDS dest = wave-uniform base (HW adds lane*16B).
static __device__ __forceinline__ void gll16(const void* g, void* l) {
    __builtin_amdgcn_global_load_lds(
        (const __attribute__((address_space(1))) void*)g,
        (__attribute__((address_space(3))) void*)l, 16, 0, 0);
}

// ---------------- k0a: enc f32 -> bf16, packed in MFMA A-fragment order ----------------
// ushort offset = strip*2^18 + kt*2^14 + frag*2^9 + lane*8 + j
// frag = mt*2 + kb; row = strip*256 + mt*16 + (lane&15); k = kt*64 + kb*32 + (lane>>4)*8 + j
__global__ __launch_bounds__(256) void kAPack(const float* __restrict__ enc,
                                              ushort* __restrict__ apk) {
    int g = blockIdx.x * 256 + threadIdx.x;     // 8,388,608 total
    int lane = g & 63;
    int frag = (g >> 6) & 31;
    int kt   = (g >> 11) & 15;
    int strip = g >> 15;                        // [0,256)
    int mt = frag >> 1, kb = frag & 1;
    int row = (strip << 8) + (mt << 4) + (lane & 15);
    int k0  = (kt << 6) + (kb << 5) + ((lane >> 4) << 3);
    const float* src = enc + (size_t)row * DIM + k0;
    float4 a = *(const float4*)src;
    float4 b = *(const float4*)(src + 4);
    union { ushort us[8]; uint4 u4; } pk;
    pk.us[0] = f2bf(a.x); pk.us[1] = f2bf(a.y); pk.us[2] = f2bf(a.z); pk.us[3] = f2bf(a.w);
    pk.us[4] = f2bf(b.x); pk.us[5] = f2bf(b.y); pk.us[6] = f2bf(b.z); pk.us[7] = f2bf(b.w);
    *(uint4*)(apk + (size_t)g * 8) = pk.u4;
}

// ---------------- k0b: Wh f32 -> bf16, fragment order (4 panels of 256 e) ----------------
__global__ __launch_bounds__(256) void kWhPack(const float* __restrict__ Wh,
                                               ushort* __restrict__ bpk) {
    int g = blockIdx.x * 256 + threadIdx.x;     // 131072 total
    int lane = g & 63;
    int frag = (g >> 6) & 31;
    int kt   = (g >> 11) & 15;
    int nb   = g >> 15;                         // [0,4)
    int ebl = frag >> 1, kbit = frag & 1;
    int e  = (nb << 8) + (ebl << 4) + (lane & 15);
    int k0 = (kt << 6) + (kbit << 5) + ((lane >> 4) << 3);
    const float* src = Wh + (size_t)e * DIM + k0;
    float4 a = *(const float4*)src;
    float4 b = *(const float4*)(src + 4);
    union { ushort us[8]; uint4 u4; } pk;
    pk.us[0] = f2bf(a.x); pk.us[1] = f2bf(a.y); pk.us[2] = f2bf(a.z); pk.us[3] = f2bf(a.w);
    pk.us[4] = f2bf(b.x); pk.us[5] = f2bf(b.y); pk.us[6] = f2bf(b.z); pk.us[7] = f2bf(b.w);
    *(uint4*)(bpk + (size_t)g * 8) = pk.u4;
}

// ---------------- k0c: base[b,e] = dec[b,:]·Ws[e,:] + bs + bh (+bc) ----------------
__global__ __launch_bounds__(256) void kBase(const float* __restrict__ dh,
                                             const float* __restrict__ Ws,
                                             const float* __restrict__ bs,
                                             const float* __restrict__ bh,
                                             const float* __restrict__ bc,
                                             const int* __restrict__ uc,
                                             float* __restrict__ base) {
    __shared__ float dec[8][DIM];
    int ec = blockIdx.x >> 2;
    int bg = blockIdx.x & 3;
    int b0 = bg * 8, e0 = ec * 32;
    int tid = threadIdx.x;
    for (int i = tid; i < 8 * DIM; i += 256) {
        int bb = i >> 10, d = i & 1023;
        float vdec = (d < 512) ? dh[(b0 + bb) * 512 + d]
                               : dh[BATCH * 512 + (b0 + bb) * 512 + d - 512];
        dec[bb][d] = vdec;
    }
    __syncthreads();
    int el = tid >> 3, ds = tid & 7;
    int e = e0 + el;
    float acc[8] = {0.f, 0.f, 0.f, 0.f, 0.f, 0.f, 0.f, 0.f};
    const float* wrow = Ws + (size_t)e * DIM;
    for (int i = 0; i < 128; ++i) {
        int d = i * 8 + ds;
        float wv = wrow[d];
#pragma unroll
        for (int bb = 0; bb < 8; ++bb) acc[bb] += wv * dec[bb][d];
    }
#pragma unroll
    for (int bb = 0; bb < 8; ++bb) {
        float s = acc[bb];
        s += __shfl_xor(s, 1); s += __shfl_xor(s, 2); s += __shfl_xor(s, 4);
        acc[bb] = s;
    }
    if (ds == 0) {
        float bias = bs[e] + bh[e] + ((*uc) ? bc[e] : 0.0f);
#pragma unroll
        for (int bb = 0; bb < 8; ++bb) base[(b0 + bb) * DIM + e] = acc[bb] + bias;
    }
}

// ---------------- k2: m97-structure GEMM + tanh + v-dot -> partial score ----------------
// BM=BN=128, BK=32, 256 thr = 4 waves (2 wm x 2 wn), wave tile 64x64, acc[4][4].
// Both operands gll16 into fragment-linear LDS (conflict-free). Per K-step:
//   STAGE(next -> other buf, 4 gll/wave)  [issued BEFORE compute]
//   8 ds_read_b128 -> 16 MFMA
//   __syncthreads()  [compiler drains vmcnt/lgkm; gll latency hidden under MFMA]
// LDS 32KB -> 3 blocks/CU (launch_bounds cap) -> cross-block wave overlap (m114).
__global__ __launch_bounds__(256, 3) void kScore(const ushort* __restrict__ apk,
                                                 const ushort* __restrict__ bpk,
                                                 const float* __restrict__ base,
                                                 const float* __restrict__ pc,
                                                 const float* __restrict__ Wc,
                                                 const float* __restrict__ vv,
                                                 const int* __restrict__ uc,
                                                 float* __restrict__ scorep) {
    __shared__ ushort Al[2][8 * 512];   // 8 frags x 1KB per buf
    __shared__ ushort Bl[2][8 * 512];
    __shared__ float red[2][128];

    const int tid = threadIdx.x;
    const int w = tid >> 6, lane = tid & 63;
    const int q = lane >> 4, l15 = lane & 15;
    const int wm = w >> 1, wn = w & 1;

    // XCD swizzle: xcd x owns m-tiles [x*64,(x+1)*64); the 8 n-panels of one m-tile
    // are consecutive on that XCD -> A-tile L2-hot, B (2MB) L2-resident per XCD.
    const int x = blockIdx.x & 7;
    const int j = blockIdx.x >> 3;          // [0,512)
    const int ms = (x << 6) + (j >> 3);     // m-tile [0,512), 128 rows
    const int np = j & 7;                   // n-panel [0,8), 128 cols
    const int b = ms >> 4;
    const int s0 = (ms & 15) << 7;

    const ushort* abase = apk + ((size_t)(ms >> 1) << 18);
    const ushort* bbase = bpk + ((size_t)(np >> 1) << 18);
    const int hM = (ms & 1) << 3;           // half-strip offset in mt units
    const int hN = (np & 1) << 3;

    // STAGE(step s, buf): wave w stages A local frags {2w,2w+1} and B local frags {2w,2w+1}
#define STAGE(S, BUF) do { \
    int kt_ = (S) >> 1, kb_ = (S) & 1; \
    const ushort* ak_ = abase + ((size_t)kt_ << 14); \
    const ushort* bk_ = bbase + ((size_t)kt_ << 14); \
    _Pragma("unroll") \
    for (int c_ = 0; c_ < 2; ++c_) { \
        int a_ = (w << 1) + c_; \
        gll16(ak_ + ((((hM + a_) << 1) + kb_) << 9) + (lane << 3), &Al[BUF][a_ << 9]); \
        gll16(bk_ + ((((hN + a_) << 1) + kb_) << 9) + (lane << 3), &Bl[BUF][a_ << 9]); \
    } } while (0)

    f32x4 acc[4][4] = {};

    // prologue
    STAGE(0, 0);
    __syncthreads();

    int buf = 0;
    for (int s = 0; s < 32; ++s) {
        if (s < 31) STAGE(s + 1, buf ^ 1);     // issue next-tile loads first
        short8 a_[4], b_[4];
#pragma unroll
        for (int mf = 0; mf < 4; ++mf)
            a_[mf] = *(const short8*)&Al[buf][(((wm << 2) + mf) << 9) + (lane << 3)];
#pragma unroll
        for (int ef = 0; ef < 4; ++ef)
            b_[ef] = *(const short8*)&Bl[buf][(((wn << 2) + ef) << 9) + (lane << 3)];
#pragma unroll
        for (int ef = 0; ef < 4; ++ef)
#pragma unroll
            for (int mf = 0; mf < 4; ++mf)
                acc[mf][ef] = __builtin_amdgcn_mfma_f32_16x16x32_bf16(a_[mf], b_[ef], acc[mf][ef], 0, 0, 0);
        __syncthreads();                        // drains gll(s+1) + all lgkm; flip
        buf ^= 1;
    }

    // ---- epilogue: partial score over this block's 128 e ----
    const float ucf = (float)(*uc);
    float basee[4], ve[4], wce[4];
#pragma unroll
    for (int ef = 0; ef < 4; ++ef) {
        int e = (np << 7) + (wn << 6) + (ef << 4) + l15;
        basee[ef] = base[b * DIM + e];
        ve[ef] = vv[e];
        wce[ef] = Wc[e] * ucf;
    }
#pragma unroll
    for (int mf = 0; mf < 4; ++mf) {
#pragma unroll
        for (int r = 0; r < 4; ++r) {
            int rl = (wm << 6) + (mf << 4) + (q << 2) + r;   // row in [0,128)
            float p = pc[b * SEQ + s0 + rl];
            float sp = 0.f;
#pragma unroll
            for (int ef = 0; ef < 4; ++ef) {
                float xv = acc[mf][ef][r] + basee[ef] + p * wce[ef];
                float tt = 1.0f - 2.0f / (1.0f + __expf(2.0f * xv));  // tanh
                sp += tt * ve[ef];
            }
            sp += __shfl_xor(sp, 1);
            sp += __shfl_xor(sp, 2);
            sp += __shfl_xor(sp, 4);
            sp += __shfl_xor(sp, 8);
            if (l15 == 0) red[wn][rl] = sp;
        }
    }
    __syncthreads();
    if (tid < 128)
        scorep[np * (BATCH * SEQ) + b * SEQ + s0 + tid] = red[0][tid] + red[1][tid];
}

// ---------------- k3: softmax (sum of 8 partials) + mask + renorm + coverage ----------------
__global__ __launch_bounds__(512) void kSoftmax(const float* __restrict__ scorep,
                                                const float* __restrict__ mask,
                                                const float* __restrict__ pc,
                                                float* __restrict__ att,
                                                float* __restrict__ cov,
                                                int write_cov) {
    __shared__ float rmax[8], rsum[8];
    const int BS = BATCH * SEQ;
    int b = blockIdx.x, tid = threadIdx.x;
    int wv = tid >> 6, ln = tid & 63;
    float x[4];
#pragma unroll
    for (int i = 0; i < 4; ++i) {
        int idx = b * SEQ + tid + i * 512;
        float s01 = scorep[idx] + scorep[BS + idx];
        float s23 = scorep[2 * BS + idx] + scorep[3 * BS + idx];
        float s45 = scorep[4 * BS + idx] + scorep[5 * BS + idx];
        float s67 = scorep[6 * BS + idx] + scorep[7 * BS + idx];
        x[i] = (s01 + s23) + (s45 + s67);
    }
    float m = fmaxf(fmaxf(x[0], x[1]), fmaxf(x[2], x[3]));
#pragma unroll
    for (int o = 1; o < 64; o <<= 1) m = fmaxf(m, __shfl_xor(m, o));
    if (ln == 0) rmax[wv] = m;
    __syncthreads();
    m = rmax[0];
#pragma unroll
    for (int i = 1; i < 8; ++i) m = fmaxf(m, rmax[i]);

    float ms[4], wm[4];
#pragma unroll
    for (int i = 0; i < 4; ++i) ms[i] = mask[b * SEQ + tid + i * 512];
    float s = 0.f;
#pragma unroll
    for (int i = 0; i < 4; ++i) { wm[i] = __expf(x[i] - m) * ms[i]; s += wm[i]; }
#pragma unroll
    for (int o = 1; o < 64; o <<= 1) s += __shfl_xor(s, o);
    if (ln == 0) rsum[wv] = s;
    __syncthreads();
    s = 0.f;
#pragma unroll
    for (int i = 0; i < 8; ++i) s += rsum[i];
    float inv = 1.0f / s;
#pragma unroll
    for (int i = 0; i < 4; ++i) {
        float wf = wm[i] * inv;
        att[b * SEQ + tid + i * 512] = wf;
        if (write_cov) cov[b * SEQ + tid + i * 512] = pc[b * SEQ + tid + i * 512] + wf;
    }
}

// ---------------- k4: context partials per 256-row strip, reading bf16 packed apk ----------------
// part[strip][d] = sum_{row in strip} att[row] * enc[row, d]   (enc via apk, half traffic)
__global__ __launch_bounds__(256) void kCtxPart(const ushort* __restrict__ apk,
                                                const float* __restrict__ att,
                                                float* __restrict__ part) {
    __shared__ float attl[256];
    const int strip = blockIdx.x;           // [0,256)
    const int tid = threadIdx.x;
    const int wv = tid >> 6, l = tid & 63;
    const int q = l >> 4, l15 = l & 15;
    attl[tid] = att[(strip << 8) + tid];
    __syncthreads();

    const ushort* sb = apk + ((size_t)strip << 18);
#pragma unroll
    for (int c = 0; c < 8; ++c) {
        int combo = (wv << 3) + c;          // [0,32): kt = combo>>1, kb = combo&1
        int kt = combo >> 1, kb = combo & 1;
        const ushort* kbase = sb + ((size_t)kt << 14) + (kb << 9) + (l << 3);
        float a8[8] = {0.f, 0.f, 0.f, 0.f, 0.f, 0.f, 0.f, 0.f};
#pragma unroll
        for (int mt = 0; mt < 16; ++mt) {
            short8 v = *(const short8*)(kbase + (mt << 10));
            float wgt = attl[(mt << 4) + l15];
#pragma unroll
            for (int jj = 0; jj < 8; ++jj) a8[jj] += wgt * bf2f((ushort)v[jj]);
        }
        // reduce across the 16 lanes sharing q (xor over l15 bits)
#pragma unroll
        for (int o = 1; o < 16; o <<= 1)
#pragma unroll
            for (int jj = 0; jj < 8; ++jj) a8[jj] += __shfl_xor(a8[jj], o);
        if (l15 == 0) {
            int d0 = (kt << 6) + (kb << 5) + (q << 3);
            float* dst = part + ((size_t)strip << 10) + d0;
#pragma unroll
            for (int jj = 0; jj < 8; ++jj) dst[jj] = a8[jj];
        }
    }
}

// ---------------- k5: deterministic reduce of 8 strip-partials per batch ----------------
__global__ __launch_bounds__(256) void kCtxReduce(const float* __restrict__ part,
                                                  float* __restrict__ ctx) {
    int g = blockIdx.x * 256 + threadIdx.x;  // 32768
    int b = g >> 10, d = g & 1023;
    float s = 0.f;
#pragma unroll
    for (int i = 0; i < 8; ++i) s += part[((size_t)((b << 3) + i) << 10) + d];
    ctx[g] = s;
}

extern "C" void kernel_launch(void* const* d_in, const int* in_sizes, int n_in,
                              void* d_out, int out_size, void* d_ws, size_t ws_size,
                              hipStream_t stream) {
    const float* dh   = (const float*)d_in[0];
    const float* enc  = (const float*)d_in[1];
    const float* mask = (const float*)d_in[2];
    const float* pc   = (const float*)d_in[3];
    const float* Wh   = (const float*)d_in[4];
    const float* bh   = (const float*)d_in[5];
    const float* Ws   = (const float*)d_in[6];
    const float* bs   = (const float*)d_in[7];
    const float* Wc   = (const float*)d_in[8];
    const float* bc   = (const float*)d_in[9];
    const float* vv   = (const float*)d_in[10];
    // d_in[11] = bv: uniform shift of scores -> softmax-invariant -> unused
    const int* uc     = (const int*)d_in[12];

    float* ctx = (float*)d_out;
    float* att = ctx + BATCH * DIM;
    float* cov = att + BATCH * SEQ;
    int write_cov = (out_size >= BATCH * (DIM + 2 * SEQ)) ? 1 : 0;

    // ws layout: apk 128MB | bpk 2MB | base 128KB | scorep 2MB | part 1MB
    ushort* apk  = (ushort*)d_ws;
    ushort* bpk  = apk + (size_t)BATCH * SEQ * DIM;            // +128MB
    float* base   = (float*)(bpk + (size_t)DIM * DIM);         // +2MB
    float* scorep = base + BATCH * DIM;
    float* part   = scorep + 8 * BATCH * SEQ;

    kAPack<<<32768, 256, 0, stream>>>(enc, apk);
    kWhPack<<<512, 256, 0, stream>>>(Wh, bpk);
    kBase<<<128, 256, 0, stream>>>(dh, Ws, bs, bh, bc, uc, base);
    kScore<<<4096, 256, 0, stream>>>(apk, bpk, base, pc, Wc, vv, uc, scorep);
    kSoftmax<<<BATCH, 512, 0, stream>>>(scorep, mask, pc, att, cov, write_cov);
    kCtxPart<<<256, 256, 0, stream>>>(apk, att, part);
    kCtxReduce<<<128, 256, 0, stream>>>(part, ctx);
}